// Round 6
// baseline (137.111 us; speedup 1.0000x reference)
//
#include <hip/hip_runtime.h>
#include <hip/hip_bf16.h>

// EdgeLearnGNN: B=16, N=64, F=1024, K=13, C=2
// Round 5: ONE mega-kernel (512 blocks x 256 threads) + 512B memset, using
// forward-only ticket barriers: after each stage a block fence-releases and takes
// a ticket; LOW tickets exit (no idle spinners), last-N arrivers run the next
// stage (chunk = ticket - offset). Polls are relaxed atomic LOADS + s_sleep
// (round-2's failure was RMW poll storms + all-block spins through tail phases).
// Work mapping is scheduling-dependent but each chunk is the same pure function
// -> bitwise-deterministic output.
//   Stage 1 (512): bid<256 spart tiles (b,ft); bid>=256 GEMM g=x@W^T (128x128xK256)
//   Stage 2 (last 256): adj[b] recompute + h2=(A+I)@g+gin_b + BN1 partials
//   Stage 3 (last 64):  BN1 reduce + folded BN1+lc mix + conv13 + BN2 partials
//   Stage 4 (ticket 63): BN2 finalize + relu + head GEMV + softmax  (zero spin)

typedef __attribute__((ext_vector_type(8))) __bf16 bf16x8;
typedef __attribute__((ext_vector_type(4))) float f32x4;

__device__ __forceinline__ unsigned short f2bf(float f) {
  union { float f; unsigned int u; } v; v.f = f;
  unsigned int r = v.u + 0x7FFFu + ((v.u >> 16) & 1u);   // RNE, finite values only
  return (unsigned short)(r >> 16);
}

union SMemU {
  struct { float xt[64 * 68]; float wt[64]; } s;                               // stage1 spart
  struct { unsigned short A[128 * 72]; unsigned short B[128 * 72]; } g;        // stage1 gemm
  struct { float adjs[64 * 65]; float csum[256]; float cinv[64];
           float gt[64 * 68]; } h;                                             // stage2
  struct { float redp[2][128]; float cls[64]; float dds[64]; float yloc[268];
           float red[256]; float red2[256]; float c0s; } y;                    // stage3
  struct { float r0[256]; float r1[256]; } hd;                                 // stage4
};

// release own work to device scope, take a ticket (old count)
__device__ __forceinline__ unsigned block_ticket(unsigned* cnt, unsigned* tks) {
  __syncthreads();                       // all waves' stores issued (+vmcnt drain)
  if (threadIdx.x == 0) {
    __threadfence();                     // release to device scope (cross-XCD)
    *tks = atomicAdd(cnt, 1u);
  }
  __syncthreads();
  return *tks;
}

// wait until all `total` blocks have released; acquire
__device__ __forceinline__ void wait_all(unsigned* cnt, unsigned total) {
  if (threadIdx.x == 0) {
    while (__hip_atomic_load(cnt, __ATOMIC_RELAXED, __HIP_MEMORY_SCOPE_AGENT) < total)
      __builtin_amdgcn_s_sleep(16);
  }
  __syncthreads();
  __threadfence();                       // acquire (all threads; invalidates stale cache)
}

__global__ __launch_bounds__(256) void mega_gnn(
    const float* __restrict__ x, const float* __restrict__ w,
    const float* __restrict__ gin_W, const float* __restrict__ gin_b,
    const float* __restrict__ bn1_g, const float* __restrict__ bn1_b,
    const float* __restrict__ lc_W, const float* __restrict__ lc_b,
    const float* __restrict__ conv_W, const float* __restrict__ conv_b,
    const float* __restrict__ bn2_g, const float* __restrict__ bn2_b,
    const float* __restrict__ out_W, const float* __restrict__ out_b,
    float* __restrict__ dout,
    float* __restrict__ spart, float* __restrict__ gpart, float* __restrict__ h2,
    float* __restrict__ part, float* __restrict__ y2, float* __restrict__ bn2part,
    unsigned* bar) {
  __shared__ SMemU sm;
  __shared__ unsigned tks;
  const int t = threadIdx.x, bid = blockIdx.x;

  // ======================= Stage 1: spart (bid<256) | GEMM (bid>=256) =======================
  if (bid < 256) {
    int b = bid >> 4, ft = bid & 15, f0 = ft * 64;
    for (int c = 0; c < 16; ++c) {
      int idx = c * 256 + t;
      int n = idx >> 6, f = idx & 63;
      sm.s.xt[n * 68 + f] = x[b * 65536 + n * 1024 + f0 + f];
    }
    if (t < 64) sm.s.wt[t] = w[f0 + t];
    __syncthreads();
    int i0 = (t >> 4) * 4, j0 = (t & 15) * 4;
    float acc[4][4];
#pragma unroll
    for (int ii = 0; ii < 4; ++ii)
#pragma unroll
      for (int jj = 0; jj < 4; ++jj) acc[ii][jj] = 0.f;
    for (int f = 0; f < 64; f += 4) {
      float4 wv = *reinterpret_cast<const float4*>(&sm.s.wt[f]);
      float4 av[4], bv[4];
#pragma unroll
      for (int ii = 0; ii < 4; ++ii) av[ii] = *reinterpret_cast<const float4*>(&sm.s.xt[(i0 + ii) * 68 + f]);
#pragma unroll
      for (int jj = 0; jj < 4; ++jj) bv[jj] = *reinterpret_cast<const float4*>(&sm.s.xt[(j0 + jj) * 68 + f]);
#pragma unroll
      for (int ii = 0; ii < 4; ++ii)
#pragma unroll
        for (int jj = 0; jj < 4; ++jj) {
          acc[ii][jj] += fabsf(av[ii].x - bv[jj].x) * wv.x
                       + fabsf(av[ii].y - bv[jj].y) * wv.y
                       + fabsf(av[ii].z - bv[jj].z) * wv.z
                       + fabsf(av[ii].w - bv[jj].w) * wv.w;
        }
    }
    float* out = spart + (size_t)bid * 4096;
#pragma unroll
    for (int ii = 0; ii < 4; ++ii)
#pragma unroll
      for (int jj = 0; jj < 4; ++jj)
        out[(i0 + ii) * 64 + (j0 + jj)] = acc[ii][jj];
  } else {
    int gb = bid - 256;
    int tile = gb >> 2, slice = gb & 3;
    int tr = tile >> 3, tc = tile & 7;
    int k0 = slice * 256;
    int wave = t >> 6, lane = t & 63;
    int wr = (wave >> 1) * 64, wc = (wave & 1) * 64;
    int lrow = lane & 15, kg = lane >> 4;
    f32x4 acc[4][4];
#pragma unroll
    for (int mi = 0; mi < 4; ++mi)
#pragma unroll
      for (int nj = 0; nj < 4; ++nj) acc[mi][nj] = f32x4{0.f, 0.f, 0.f, 0.f};
    for (int chunk = 0; chunk < 4; ++chunk) {
      int kc = k0 + chunk * 64;
#pragma unroll
      for (int u = 0; u < 8; ++u) {
        int idx4 = u * 256 + t;
        int row = idx4 >> 4, kq = idx4 & 15;
        float4 va = *reinterpret_cast<const float4*>(&x[(size_t)(tr * 128 + row) * 1024 + kc + kq * 4]);
        ushort4 ua; ua.x = f2bf(va.x); ua.y = f2bf(va.y); ua.z = f2bf(va.z); ua.w = f2bf(va.w);
        *reinterpret_cast<ushort4*>(&sm.g.A[row * 72 + kq * 4]) = ua;
        float4 vb = *reinterpret_cast<const float4*>(&gin_W[(size_t)(tc * 128 + row) * 1024 + kc + kq * 4]);
        ushort4 ub; ub.x = f2bf(vb.x); ub.y = f2bf(vb.y); ub.z = f2bf(vb.z); ub.w = f2bf(vb.w);
        *reinterpret_cast<ushort4*>(&sm.g.B[row * 72 + kq * 4]) = ub;
      }
      __syncthreads();
#pragma unroll
      for (int ks = 0; ks < 2; ++ks) {
        bf16x8 af[4], bf_[4];
#pragma unroll
        for (int mi = 0; mi < 4; ++mi)
          af[mi] = *reinterpret_cast<const bf16x8*>(&sm.g.A[(wr + mi * 16 + lrow) * 72 + ks * 32 + kg * 8]);
#pragma unroll
        for (int nj = 0; nj < 4; ++nj)
          bf_[nj] = *reinterpret_cast<const bf16x8*>(&sm.g.B[(wc + nj * 16 + lrow) * 72 + ks * 32 + kg * 8]);
#pragma unroll
        for (int mi = 0; mi < 4; ++mi)
#pragma unroll
          for (int nj = 0; nj < 4; ++nj)
            acc[mi][nj] = __builtin_amdgcn_mfma_f32_16x16x32_bf16(af[mi], bf_[nj], acc[mi][nj], 0, 0, 0);
      }
      __syncthreads();
    }
    float* gp = gpart + (size_t)slice * (1024u * 1024u);
#pragma unroll
    for (int mi = 0; mi < 4; ++mi) {
      int row = tr * 128 + wr + mi * 16 + kg * 4;
#pragma unroll
      for (int nj = 0; nj < 4; ++nj) {
        int col = tc * 128 + wc + nj * 16 + lrow;
#pragma unroll
        for (int r = 0; r < 4; ++r)
          gp[(size_t)(row + r) * 1024 + col] = acc[mi][nj][r];
      }
    }
  }

  // --- barrier 0: 512 arrive; last 256 continue ---
  unsigned t0 = block_ticket(&bar[0], &tks);
  if (t0 < 256u) return;
  wait_all(&bar[0], 512u);
  {
    // ================== Stage 2: adj + h2 + BN1 partials, chunk c=(b,ft) ==================
    int c = (int)(t0 - 256u);
    int b = c >> 4, ft = c & 15, f0 = ft * 64;
    {
      int i = t >> 4, fl = (t & 15) * 4;
#pragma unroll
      for (int q4 = 0; q4 < 4; ++q4) {
        int row = q4 * 16 + i;
        const float* base = gpart + (size_t)(b * 64 + row) * 1024 + f0 + fl;
        float4 s0 = *reinterpret_cast<const float4*>(base);
        float4 s1 = *reinterpret_cast<const float4*>(base + (1u << 20));
        float4 s2 = *reinterpret_cast<const float4*>(base + (2u << 20));
        float4 s3 = *reinterpret_cast<const float4*>(base + (3u << 20));
        float4 g4;
        g4.x = (s0.x + s1.x) + (s2.x + s3.x);
        g4.y = (s0.y + s1.y) + (s2.y + s3.y);
        g4.z = (s0.z + s1.z) + (s2.z + s3.z);
        g4.w = (s0.w + s1.w) + (s2.w + s3.w);
        *reinterpret_cast<float4*>(&sm.h.gt[row * 68 + fl]) = g4;
      }
    }
    int jl = t & 63, q = t >> 6;
    float v[16];
#pragma unroll
    for (int r = 0; r < 16; ++r) v[r] = 0.f;
    for (int ft2 = 0; ft2 < 16; ++ft2) {
      const float* p = spart + (size_t)(b * 16 + ft2) * 4096 + jl;
#pragma unroll
      for (int r = 0; r < 16; ++r) v[r] += p[(q * 16 + r) * 64];
    }
    float partsum = 0.f;
#pragma unroll
    for (int r = 0; r < 16; ++r) {
      float e = expf(-fmaxf(v[r], 0.f));
      sm.h.adjs[(q * 16 + r) * 65 + jl] = e;
      partsum += e;
    }
    sm.h.csum[q * 64 + jl] = partsum;
    __syncthreads();
    if (t < 64)
      sm.h.cinv[t] = 1.f / (sm.h.csum[t] + sm.h.csum[64 + t] + sm.h.csum[128 + t] + sm.h.csum[192 + t]);
    __syncthreads();
    float ci = sm.h.cinv[jl];
    float* doutAdj = dout + 32 + (size_t)b * 4096;
#pragma unroll
    for (int r = 0; r < 16; ++r) {
      float a = sm.h.adjs[(q * 16 + r) * 65 + jl] * ci;
      sm.h.adjs[(q * 16 + r) * 65 + jl] = a;
      if (ft == 0) doutAdj[(q * 16 + r) * 64 + jl] = a;
    }
    __syncthreads();
    int i0 = (t >> 4) * 4, fl = (t & 15) * 4;
    float4 gbv = *reinterpret_cast<const float4*>(&gin_b[f0 + fl]);
    float4 acc4[4];
#pragma unroll
    for (int ii = 0; ii < 4; ++ii)
      acc4[ii] = *reinterpret_cast<const float4*>(&sm.h.gt[(i0 + ii) * 68 + fl]);  // identity
    for (int j = 0; j < 64; ++j) {
      float4 gv = *reinterpret_cast<const float4*>(&sm.h.gt[j * 68 + fl]);
#pragma unroll
      for (int ii = 0; ii < 4; ++ii) {
        float a = sm.h.adjs[(i0 + ii) * 65 + j];
        acc4[ii].x += a * gv.x; acc4[ii].y += a * gv.y;
        acc4[ii].z += a * gv.z; acc4[ii].w += a * gv.w;
      }
    }
    float rs[4], rq[4];
#pragma unroll
    for (int ii = 0; ii < 4; ++ii) {
      acc4[ii].x += gbv.x; acc4[ii].y += gbv.y; acc4[ii].z += gbv.z; acc4[ii].w += gbv.w;
      *reinterpret_cast<float4*>(&h2[(size_t)(b * 64 + i0 + ii) * 1024 + f0 + fl]) = acc4[ii];
      rs[ii] = (acc4[ii].x + acc4[ii].y) + (acc4[ii].z + acc4[ii].w);
      rq[ii] = (acc4[ii].x * acc4[ii].x + acc4[ii].y * acc4[ii].y)
             + (acc4[ii].z * acc4[ii].z + acc4[ii].w * acc4[ii].w);
    }
#pragma unroll
    for (int m = 1; m < 16; m <<= 1) {
#pragma unroll
      for (int r = 0; r < 4; ++r) {
        rs[r] += __shfl_xor(rs[r], m, 64);
        rq[r] += __shfl_xor(rq[r], m, 64);
      }
    }
    if ((t & 15) == 0) {
      float* pp = part + (size_t)c * 128;
#pragma unroll
      for (int r = 0; r < 4; ++r) {
        int n = i0 + r;
        pp[2 * n]     = rs[r];
        pp[2 * n + 1] = rq[r];
      }
    }
  }

  // --- barrier 1: 256 arrive; last 64 continue ---
  unsigned t1 = block_ticket(&bar[32], &tks);
  if (t1 < 192u) return;
  wait_all(&bar[32], 256u);
  int dchunk;
  {
    // ========= Stage 3: BN1 reduce + folded mix + conv13 + BN2 partials, chunk d =========
    dchunk = (int)(t1 - 192u);
    int b = dchunk >> 2, fq = dchunk & 3;
    int f0 = fq * 256;
    {
      int k = t & 127, h = t >> 7;
      float s = 0.f;
      const float* pp = part + (size_t)h * 128 * 128 + k;
      for (int p = 0; p < 128; ++p) s += pp[(size_t)p * 128];
      sm.y.redp[h][k] = s;
    }
    __syncthreads();
    if (t < 64) {
      float sum = sm.y.redp[0][2 * t] + sm.y.redp[1][2 * t];
      float sq  = sm.y.redp[0][2 * t + 1] + sm.y.redp[1][2 * t + 1];
      float m = sum * (1.f / 16384.f);
      float var = sq * (1.f / 16384.f) - m * m;     // biased, as jnp.var
      float inv = 1.f / sqrtf(var + 1e-5f);
      float g = bn1_g[t], be = bn1_b[t], lw = lc_W[t];
      sm.y.cls[t] = lw * g * inv;
      sm.y.dds[t] = lw * (be - m * inv * g);
    }
    __syncthreads();
    if (t == 0) {
      float s = 0.f;
      for (int n = 0; n < 64; ++n) s += sm.y.dds[n];
      sm.y.c0s = s + lc_b[0];
    }
    __syncthreads();
    float c0 = sm.y.c0s;
    for (int idx = t; idx < 268; idx += 256) {
      int f = f0 - 6 + idx;
      float acc = 0.f;
      if (f >= 0 && f < 1024) {
        acc = c0;
        const float* col = h2 + (size_t)(b * 64) * 1024 + f;
        for (int n = 0; n < 64; ++n) acc += sm.y.cls[n] * col[(size_t)n * 1024];
      }
      sm.y.yloc[idx] = acc;
    }
    __syncthreads();
    float cw[13];
#pragma unroll
    for (int k = 0; k < 13; ++k) cw[k] = conv_W[k];
    float vv = conv_b[0];
#pragma unroll
    for (int k = 0; k < 13; ++k) vv += sm.y.yloc[t + k] * cw[k];
    y2[b * 1024 + f0 + t] = vv;
    sm.y.red[t] = vv; sm.y.red2[t] = vv * vv;
    __syncthreads();
    for (int off = 128; off > 0; off >>= 1) {
      if (t < off) { sm.y.red[t] += sm.y.red[t + off]; sm.y.red2[t] += sm.y.red2[t + off]; }
      __syncthreads();
    }
    if (t == 0) { bn2part[2 * dchunk] = sm.y.red[0]; bn2part[2 * dchunk + 1] = sm.y.red2[0]; }
  }

  // --- barrier 2: 64 arrive; ticket 63 (the 64th) continues, zero spin ---
  unsigned t2 = block_ticket(&bar[64], &tks);
  if (t2 < 63u) return;
  wait_all(&bar[64], 64u);     // passes immediately; provides the acquire fence
  {
    // ============ Stage 4: BN2 finalize + relu + head GEMV + softmax ============
    float S = 0.f, S2 = 0.f;
    for (int i = 0; i < 64; ++i) { S += bn2part[2 * i]; S2 += bn2part[2 * i + 1]; }
    float m2 = S * (1.f / 16384.f);
    float inv2 = 1.f / sqrtf(S2 * (1.f / 16384.f) - m2 * m2 + 1e-5f);
    float g2 = bn2_g[0] * inv2, be2 = bn2_b[0];
    int hb = t >> 4, seg = t & 15;
    const float4* yv = reinterpret_cast<const float4*>(&y2[hb * 1024 + seg * 64]);
    const float4* w0 = reinterpret_cast<const float4*>(&out_W[seg * 64]);
    const float4* w1 = reinterpret_cast<const float4*>(&out_W[1024 + seg * 64]);
    float a0 = 0.f, a1 = 0.f;
#pragma unroll 4
    for (int u = 0; u < 16; ++u) {
      float4 y4 = yv[u], c0 = w0[u], c1 = w1[u];
      float vx = fmaxf((y4.x - m2) * g2 + be2, 0.f);
      float vy = fmaxf((y4.y - m2) * g2 + be2, 0.f);
      float vz = fmaxf((y4.z - m2) * g2 + be2, 0.f);
      float vw = fmaxf((y4.w - m2) * g2 + be2, 0.f);
      a0 += vx * c0.x + vy * c0.y + vz * c0.z + vw * c0.w;
      a1 += vx * c1.x + vy * c1.y + vz * c1.z + vw * c1.w;
    }
    sm.hd.r0[t] = a0; sm.hd.r1[t] = a1;
    __syncthreads();
    for (int off = 8; off > 0; off >>= 1) {
      if (seg < off) { sm.hd.r0[t] += sm.hd.r0[t + off]; sm.hd.r1[t] += sm.hd.r1[t + off]; }
      __syncthreads();
    }
    if (seg == 0) {
      float l0 = sm.hd.r0[t] + out_b[0], l1 = sm.hd.r1[t] + out_b[1];
      float mx = fmaxf(l0, l1);
      float e0 = expf(l0 - mx), e1 = expf(l1 - mx);
      float inv = 1.f / (e0 + e1);
      dout[hb * 2 + 0] = e0 * inv;
      dout[hb * 2 + 1] = e1 * inv;
    }
  }
}

extern "C" void kernel_launch(void* const* d_in, const int* in_sizes, int n_in,
                              void* d_out, int out_size, void* d_ws, size_t ws_size,
                              hipStream_t stream) {
  (void)in_sizes; (void)n_in; (void)out_size; (void)ws_size;
  const float* x      = (const float*)d_in[0];
  const float* w      = (const float*)d_in[1];
  const float* gin_W  = (const float*)d_in[2];
  const float* gin_b  = (const float*)d_in[3];
  const float* bn1_g  = (const float*)d_in[4];
  const float* bn1_b  = (const float*)d_in[5];
  const float* lc_W   = (const float*)d_in[6];
  const float* lc_b   = (const float*)d_in[7];
  const float* conv_W = (const float*)d_in[8];
  const float* conv_b = (const float*)d_in[9];
  const float* bn2_g  = (const float*)d_in[10];
  const float* bn2_b  = (const float*)d_in[11];
  const float* out_W  = (const float*)d_in[12];
  const float* out_b  = (const float*)d_in[13];
  float* dout = (float*)d_out;

  char* ws = (char*)d_ws;
  float* spart   = (float*)ws;                                  // 4 MB
  float* h2      = (float*)(ws + (4u << 20));                   // 4 MB
  float* gpart   = (float*)(ws + (8u << 20));                   // 16 MB (4 k-slices)
  float* part    = (float*)(ws + (24u << 20));                  // 128 KB
  float* y2      = (float*)(ws + (24u << 20) + (128u << 10));   // 64 KB
  float* bn2part = (float*)(ws + (24u << 20) + (192u << 10));   // 512 B
  unsigned* bar  = (unsigned*)(ws + (25u << 20));               // 3 counters, 128B apart

  hipMemsetAsync(bar, 0, 512, stream);
  mega_gnn<<<dim3(512), dim3(256), 0, stream>>>(
      x, w, gin_W, gin_b, bn1_g, bn1_b, lc_W, lc_b, conv_W, conv_b,
      bn2_g, bn2_b, out_W, out_b, dout,
      spart, gpart, h2, part, y2, bn2part, bar);
}

// Round 7
// 68.722 us; speedup vs baseline: 1.9952x; 1.9952x over previous
//
#include <hip/hip_runtime.h>
#include <hip/hip_bf16.h>

// EdgeLearnGNN: B=16, N=64, F=1024, K=13, C=2
// Round 6: r4's 4-kernel chain (in-kernel device barriers are proven losers:
// each device-scope fence forces per-XCD L2 writeback/invalidate -> r6 mega ran
// at 420 GB/s latency-bound). This round kills the two 64MB redundancies:
//  - K1 GEMM: XCD-region tile mapping (bid%8 = XCD round-robin): each XCD owns a
//    2x4 tile region, both K-slices co-located -> 3MB footprint, L2-resident.
//    K-slice 4->2: gpart 16MB->8MB f32.
//  - K2: 16 blocks of batch b land on one XCD -> spart[b] (256KB) + g[b] (1MB)
//    L2-resident instead of 64MB of L3 re-reads. K3 matches the b->XCD map.
//   K1: 384 blocks: 256 spart tiles (b,ft) | 128 GEMM g=x@W^T (128^2 x K512)
//   K2: 256 blocks (b,ft): adj recompute + h2=(A+I)@g+gin_b + BN1 partials
//   K3: 64 blocks: BN1 reduce + folded BN1+lc mix + conv13 + BN2 partials
//   K4: 1 block: BN2 finalize + relu + head GEMV + softmax

typedef __attribute__((ext_vector_type(8))) __bf16 bf16x8;
typedef __attribute__((ext_vector_type(4))) float f32x4;

__device__ __forceinline__ unsigned short f2bf(float f) {
  union { float f; unsigned int u; } v; v.f = f;
  unsigned int r = v.u + 0x7FFFu + ((v.u >> 16) & 1u);   // RNE, finite values only
  return (unsigned short)(r >> 16);
}

// ---------------- K1: spart tiles (bid<256) + XCD-local GEMM (bid>=256) ----------------
__global__ __launch_bounds__(256) void k1_spart_gemm(
    const float* __restrict__ x, const float* __restrict__ w,
    const float* __restrict__ gin_W,
    float* __restrict__ spart, float* __restrict__ gpart) {
  __shared__ __align__(16) union {
    struct { float xt[64 * 68]; float wt[64]; } s;
    struct { unsigned short A[128 * 72]; unsigned short B[128 * 72]; } g;
  } sm;
  int t = threadIdx.x, bid = blockIdx.x;

  if (bid < 256) {
    // ----- pairwise weighted-L1 partial scores, tile (b, ft) -----
    int b = bid >> 4, ft = bid & 15, f0 = ft * 64;
    for (int c = 0; c < 16; ++c) {
      int idx = c * 256 + t;
      int n = idx >> 6, f = idx & 63;
      sm.s.xt[n * 68 + f] = x[b * 65536 + n * 1024 + f0 + f];
    }
    if (t < 64) sm.s.wt[t] = w[f0 + t];
    __syncthreads();
    int i0 = (t >> 4) * 4, j0 = (t & 15) * 4;
    float acc[4][4];
#pragma unroll
    for (int ii = 0; ii < 4; ++ii)
#pragma unroll
      for (int jj = 0; jj < 4; ++jj) acc[ii][jj] = 0.f;
    for (int f = 0; f < 64; f += 4) {
      float4 wv = *reinterpret_cast<const float4*>(&sm.s.wt[f]);
      float4 av[4], bv[4];
#pragma unroll
      for (int ii = 0; ii < 4; ++ii) av[ii] = *reinterpret_cast<const float4*>(&sm.s.xt[(i0 + ii) * 68 + f]);
#pragma unroll
      for (int jj = 0; jj < 4; ++jj) bv[jj] = *reinterpret_cast<const float4*>(&sm.s.xt[(j0 + jj) * 68 + f]);
#pragma unroll
      for (int ii = 0; ii < 4; ++ii)
#pragma unroll
        for (int jj = 0; jj < 4; ++jj) {
          acc[ii][jj] += fabsf(av[ii].x - bv[jj].x) * wv.x
                       + fabsf(av[ii].y - bv[jj].y) * wv.y
                       + fabsf(av[ii].z - bv[jj].z) * wv.z
                       + fabsf(av[ii].w - bv[jj].w) * wv.w;
        }
    }
    float* out = spart + (size_t)bid * 4096;
#pragma unroll
    for (int ii = 0; ii < 4; ++ii)
#pragma unroll
      for (int jj = 0; jj < 4; ++jj)
        out[(i0 + ii) * 64 + (j0 + jj)] = acc[ii][jj];
    return;
  }

  // ----- GEMM g = x @ W^T: 128 blocks, tile 128x128, K-slice 512, XCD regions -----
  // xcd = g&7 (bid%8 round-robin, 256%8==0). XCD owns tiles rows {2*(xcd&3)+0,1},
  // cols {4*(xcd>>2)+0..3}, both slices -> A 1MB + B 2MB footprint, L2-resident.
  int g = bid - 256;
  int xcd = g & 7, idx = g >> 3;
  int lt = idx & 7, slice = idx >> 3;
  int tr = 2 * (xcd & 3) + (lt >> 2);
  int tc = 4 * (xcd >> 2) + (lt & 3);
  int k0 = slice * 512;
  int wave = t >> 6, lane = t & 63;
  int wr = (wave >> 1) * 64, wc = (wave & 1) * 64;
  int lrow = lane & 15, kg = lane >> 4;
  f32x4 acc[4][4];
#pragma unroll
  for (int mi = 0; mi < 4; ++mi)
#pragma unroll
    for (int nj = 0; nj < 4; ++nj) acc[mi][nj] = f32x4{0.f, 0.f, 0.f, 0.f};

  for (int chunk = 0; chunk < 8; ++chunk) {
    int kc = k0 + chunk * 64;
#pragma unroll
    for (int u = 0; u < 8; ++u) {
      int idx4 = u * 256 + t;
      int row = idx4 >> 4, kq = idx4 & 15;
      float4 va = *reinterpret_cast<const float4*>(&x[(size_t)(tr * 128 + row) * 1024 + kc + kq * 4]);
      ushort4 ua; ua.x = f2bf(va.x); ua.y = f2bf(va.y); ua.z = f2bf(va.z); ua.w = f2bf(va.w);
      *reinterpret_cast<ushort4*>(&sm.g.A[row * 72 + kq * 4]) = ua;
      float4 vb = *reinterpret_cast<const float4*>(&gin_W[(size_t)(tc * 128 + row) * 1024 + kc + kq * 4]);
      ushort4 ub; ub.x = f2bf(vb.x); ub.y = f2bf(vb.y); ub.z = f2bf(vb.z); ub.w = f2bf(vb.w);
      *reinterpret_cast<ushort4*>(&sm.g.B[row * 72 + kq * 4]) = ub;
    }
    __syncthreads();
#pragma unroll
    for (int ks = 0; ks < 2; ++ks) {
      bf16x8 af[4], bf_[4];
#pragma unroll
      for (int mi = 0; mi < 4; ++mi)
        af[mi] = *reinterpret_cast<const bf16x8*>(&sm.g.A[(wr + mi * 16 + lrow) * 72 + ks * 32 + kg * 8]);
#pragma unroll
      for (int nj = 0; nj < 4; ++nj)
        bf_[nj] = *reinterpret_cast<const bf16x8*>(&sm.g.B[(wc + nj * 16 + lrow) * 72 + ks * 32 + kg * 8]);
#pragma unroll
      for (int mi = 0; mi < 4; ++mi)
#pragma unroll
        for (int nj = 0; nj < 4; ++nj)
          acc[mi][nj] = __builtin_amdgcn_mfma_f32_16x16x32_bf16(af[mi], bf_[nj], acc[mi][nj], 0, 0, 0);
    }
    __syncthreads();
  }
  float* gp = gpart + (size_t)slice * (1024u * 1024u);
#pragma unroll
  for (int mi = 0; mi < 4; ++mi) {
    int row = tr * 128 + wr + mi * 16 + kg * 4;     // C/D: row = (lane>>4)*4 + reg
#pragma unroll
    for (int nj = 0; nj < 4; ++nj) {
      int col = tc * 128 + wc + nj * 16 + lrow;     // col = lane&15
#pragma unroll
      for (int r = 0; r < 4; ++r)
        gp[(size_t)(row + r) * 1024 + col] = acc[mi][nj][r];
    }
  }
}

// ---- K2: adj[b] recompute + h2 = (A+I)@g + gin_b + BN1 partials. ----
// XCD-swizzled: the 16 blocks of batch b share one XCD -> spart[b]+g[b] L2-hit.
__global__ __launch_bounds__(256) void k2_adj_h2(
    const float* __restrict__ spart, const float* __restrict__ gpart,
    const float* __restrict__ gin_b,
    float* __restrict__ dout, float* __restrict__ h2, float* __restrict__ part) {
  __shared__ float adjs[64 * 65];
  __shared__ float csum[256];
  __shared__ float cinv[64];
  __shared__ __align__(16) float gt[64 * 68];
  int t = threadIdx.x, bid = blockIdx.x;
  int xcd = bid & 7, local = bid >> 3;
  int b = (xcd << 1) | (local & 1);
  int ft = local >> 1;
  int f0 = ft * 64;
  // g tile: sum the 2 K-slice partials -> gt[64][68]
  {
    int i = t >> 4, fl = (t & 15) * 4;
#pragma unroll
    for (int c = 0; c < 4; ++c) {
      int row = c * 16 + i;
      const float* base = gpart + (size_t)(b * 64 + row) * 1024 + f0 + fl;
      float4 s0 = *reinterpret_cast<const float4*>(base);
      float4 s1 = *reinterpret_cast<const float4*>(base + (1u << 20));
      float4 g4;
      g4.x = s0.x + s1.x; g4.y = s0.y + s1.y;
      g4.z = s0.z + s1.z; g4.w = s0.w + s1.w;
      *reinterpret_cast<float4*>(&gt[row * 68 + fl]) = g4;
    }
  }
  // adj[b] from spart (redundant per ft; ft==0 writes to dout)
  int jl = t & 63, q = t >> 6;
  float v[16];
#pragma unroll
  for (int r = 0; r < 16; ++r) v[r] = 0.f;
  for (int ft2 = 0; ft2 < 16; ++ft2) {
    const float* p = spart + (size_t)(b * 16 + ft2) * 4096 + jl;
#pragma unroll
    for (int r = 0; r < 16; ++r) v[r] += p[(q * 16 + r) * 64];
  }
  float partsum = 0.f;
#pragma unroll
  for (int r = 0; r < 16; ++r) {
    float e = expf(-fmaxf(v[r], 0.f));
    adjs[(q * 16 + r) * 65 + jl] = e;
    partsum += e;
  }
  csum[q * 64 + jl] = partsum;
  __syncthreads();
  if (t < 64)
    cinv[t] = 1.f / (csum[t] + csum[64 + t] + csum[128 + t] + csum[192 + t]);
  __syncthreads();
  float ci = cinv[jl];
  float* doutAdj = dout + 32 + (size_t)b * 4096;
#pragma unroll
  for (int r = 0; r < 16; ++r) {
    float a = adjs[(q * 16 + r) * 65 + jl] * ci;
    adjs[(q * 16 + r) * 65 + jl] = a;
    if (ft == 0) doutAdj[(q * 16 + r) * 64 + jl] = a;
  }
  __syncthreads();
  // h2 tile = gt (identity) + adj@gt + gin_b; BN1 partials over the tile's 64 cols
  int i0 = (t >> 4) * 4, fl = (t & 15) * 4;
  float4 gbv = *reinterpret_cast<const float4*>(&gin_b[f0 + fl]);
  float4 acc4[4];
#pragma unroll
  for (int ii = 0; ii < 4; ++ii)
    acc4[ii] = *reinterpret_cast<const float4*>(&gt[(i0 + ii) * 68 + fl]);  // identity
  for (int j = 0; j < 64; ++j) {
    float4 gv = *reinterpret_cast<const float4*>(&gt[j * 68 + fl]);
#pragma unroll
    for (int ii = 0; ii < 4; ++ii) {
      float a = adjs[(i0 + ii) * 65 + j];
      acc4[ii].x += a * gv.x; acc4[ii].y += a * gv.y;
      acc4[ii].z += a * gv.z; acc4[ii].w += a * gv.w;
    }
  }
  float rs[4], rq[4];
#pragma unroll
  for (int ii = 0; ii < 4; ++ii) {
    acc4[ii].x += gbv.x; acc4[ii].y += gbv.y; acc4[ii].z += gbv.z; acc4[ii].w += gbv.w;
    *reinterpret_cast<float4*>(&h2[(size_t)(b * 64 + i0 + ii) * 1024 + f0 + fl]) = acc4[ii];
    rs[ii] = (acc4[ii].x + acc4[ii].y) + (acc4[ii].z + acc4[ii].w);
    rq[ii] = (acc4[ii].x * acc4[ii].x + acc4[ii].y * acc4[ii].y)
           + (acc4[ii].z * acc4[ii].z + acc4[ii].w * acc4[ii].w);
  }
#pragma unroll
  for (int m = 1; m < 16; m <<= 1) {
#pragma unroll
    for (int r = 0; r < 4; ++r) {
      rs[r] += __shfl_xor(rs[r], m, 64);
      rq[r] += __shfl_xor(rq[r], m, 64);
    }
  }
  if ((t & 15) == 0) {
    float* pp = part + (size_t)(b * 16 + ft) * 128;
#pragma unroll
    for (int r = 0; r < 4; ++r) {
      int n = i0 + r;
      pp[2 * n]     = rs[r];
      pp[2 * n + 1] = rq[r];
    }
  }
}

// ---- K3: 64 blocks (b, 256-f quarter), b->XCD map matches K2. BN1 reduce +
//      folded BN1+lc channel-mix + conv13 (halo recomputed) + BN2 partials. ----
__global__ __launch_bounds__(256) void k3_y(
    const float* __restrict__ h2, const float* __restrict__ part,
    const float* __restrict__ lc_W, const float* __restrict__ lc_b,
    const float* __restrict__ bn1_g, const float* __restrict__ bn1_b,
    const float* __restrict__ conv_W, const float* __restrict__ conv_b,
    float* __restrict__ y2, float* __restrict__ bn2part) {
  __shared__ float redp[2][128];
  __shared__ float cls[64], dds[64];
  __shared__ float yloc[268];
  __shared__ float red[256], red2[256];
  __shared__ float c0s;
  int t = threadIdx.x, bid = blockIdx.x;
  int b = ((bid & 7) << 1) | ((bid >> 3) & 1);
  int fq = bid >> 4;
  int f0 = fq * 256;
  {
    int k = t & 127, h = t >> 7;
    float s = 0.f;
    const float* pp = part + (size_t)h * 128 * 128 + k;
    for (int p = 0; p < 128; ++p) s += pp[(size_t)p * 128];
    redp[h][k] = s;
  }
  __syncthreads();
  if (t < 64) {
    float sum = redp[0][2 * t] + redp[1][2 * t];
    float sq  = redp[0][2 * t + 1] + redp[1][2 * t + 1];
    float m = sum * (1.f / 16384.f);
    float var = sq * (1.f / 16384.f) - m * m;     // biased, as jnp.var
    float inv = 1.f / sqrtf(var + 1e-5f);
    float g = bn1_g[t], be = bn1_b[t], lw = lc_W[t];
    cls[t] = lw * g * inv;
    dds[t] = lw * (be - m * inv * g);
  }
  __syncthreads();
  if (t == 0) {
    float s = 0.f;
    for (int n = 0; n < 64; ++n) s += dds[n];
    c0s = s + lc_b[0];
  }
  __syncthreads();
  float c0 = c0s;
  for (int idx = t; idx < 268; idx += 256) {
    int f = f0 - 6 + idx;
    float acc = 0.f;
    if (f >= 0 && f < 1024) {
      acc = c0;
      const float* col = h2 + (size_t)(b * 64) * 1024 + f;
      for (int n = 0; n < 64; ++n) acc += cls[n] * col[(size_t)n * 1024];
    }
    yloc[idx] = acc;
  }
  __syncthreads();
  float cw[13];
#pragma unroll
  for (int k = 0; k < 13; ++k) cw[k] = conv_W[k];
  float vv = conv_b[0];
#pragma unroll
  for (int k = 0; k < 13; ++k) vv += yloc[t + k] * cw[k];
  y2[b * 1024 + f0 + t] = vv;
  red[t] = vv; red2[t] = vv * vv;
  __syncthreads();
  for (int off = 128; off > 0; off >>= 1) {
    if (t < off) { red[t] += red[t + off]; red2[t] += red2[t + off]; }
    __syncthreads();
  }
  if (t == 0) {
    int dchunk = b * 4 + fq;
    bn2part[2 * dchunk] = red[0]; bn2part[2 * dchunk + 1] = red2[0];
  }
}

// ---- K4: BN2 finalize + relu + head GEMV (16x1024x2, float4) + softmax ----
__global__ __launch_bounds__(256) void k4_head(
    const float* __restrict__ y2, const float* __restrict__ bn2part,
    const float* __restrict__ bn2_g, const float* __restrict__ bn2_b,
    const float* __restrict__ out_W, const float* __restrict__ out_b,
    float* __restrict__ dout) {
  int t = threadIdx.x;
  float S = 0.f, S2 = 0.f;
  for (int i = 0; i < 64; ++i) { S += bn2part[2 * i]; S2 += bn2part[2 * i + 1]; }
  float m2 = S * (1.f / 16384.f);
  float inv2 = 1.f / sqrtf(S2 * (1.f / 16384.f) - m2 * m2 + 1e-5f);
  float g2 = bn2_g[0] * inv2, be2 = bn2_b[0];
  int b = t >> 4, seg = t & 15;
  const float4* yv = reinterpret_cast<const float4*>(&y2[b * 1024 + seg * 64]);
  const float4* w0 = reinterpret_cast<const float4*>(&out_W[seg * 64]);
  const float4* w1 = reinterpret_cast<const float4*>(&out_W[1024 + seg * 64]);
  float a0 = 0.f, a1 = 0.f;
#pragma unroll 4
  for (int u = 0; u < 16; ++u) {
    float4 y4 = yv[u], c0 = w0[u], c1 = w1[u];
    float vx = fmaxf((y4.x - m2) * g2 + be2, 0.f);
    float vy = fmaxf((y4.y - m2) * g2 + be2, 0.f);
    float vz = fmaxf((y4.z - m2) * g2 + be2, 0.f);
    float vw = fmaxf((y4.w - m2) * g2 + be2, 0.f);
    a0 += vx * c0.x + vy * c0.y + vz * c0.z + vw * c0.w;
    a1 += vx * c1.x + vy * c1.y + vz * c1.z + vw * c1.w;
  }
  __shared__ float r0[256], r1[256];
  r0[t] = a0; r1[t] = a1;
  __syncthreads();
  for (int off = 8; off > 0; off >>= 1) {
    if (seg < off) { r0[t] += r0[t + off]; r1[t] += r1[t + off]; }
    __syncthreads();
  }
  if (seg == 0) {
    float l0 = r0[t] + out_b[0], l1 = r1[t] + out_b[1];
    float mx = fmaxf(l0, l1);
    float e0 = expf(l0 - mx), e1 = expf(l1 - mx);
    float inv = 1.f / (e0 + e1);
    dout[b * 2 + 0] = e0 * inv;
    dout[b * 2 + 1] = e1 * inv;
  }
}

extern "C" void kernel_launch(void* const* d_in, const int* in_sizes, int n_in,
                              void* d_out, int out_size, void* d_ws, size_t ws_size,
                              hipStream_t stream) {
  (void)in_sizes; (void)n_in; (void)out_size; (void)ws_size;
  const float* x      = (const float*)d_in[0];
  const float* w      = (const float*)d_in[1];
  const float* gin_W  = (const float*)d_in[2];
  const float* gin_b  = (const float*)d_in[3];
  const float* bn1_g  = (const float*)d_in[4];
  const float* bn1_b  = (const float*)d_in[5];
  const float* lc_W   = (const float*)d_in[6];
  const float* lc_b   = (const float*)d_in[7];
  const float* conv_W = (const float*)d_in[8];
  const float* conv_b = (const float*)d_in[9];
  const float* bn2_g  = (const float*)d_in[10];
  const float* bn2_b  = (const float*)d_in[11];
  const float* out_W  = (const float*)d_in[12];
  const float* out_b  = (const float*)d_in[13];
  float* dout = (float*)d_out;

  char* ws = (char*)d_ws;
  float* spart   = (float*)ws;                                  // 4 MB
  float* h2      = (float*)(ws + (4u << 20));                   // 4 MB
  float* gpart   = (float*)(ws + (8u << 20));                   // 8 MB (2 K-slices)
  float* part    = (float*)(ws + (16u << 20));                  // 128 KB (256 x 128 f32)
  float* y2      = (float*)(ws + (16u << 20) + (128u << 10));   // 64 KB
  float* bn2part = (float*)(ws + (16u << 20) + (192u << 10));   // 128 f32

  k1_spart_gemm<<<dim3(384), dim3(256), 0, stream>>>(x, w, gin_W, spart, gpart);
  k2_adj_h2    <<<dim3(256), dim3(256), 0, stream>>>(spart, gpart, gin_b, dout, h2, part);
  k3_y         <<<dim3(64),  dim3(256), 0, stream>>>(h2, part, lc_W, lc_b, bn1_g, bn1_b,
                                                     conv_W, conv_b, y2, bn2part);
  k4_head      <<<dim3(1),   dim3(256), 0, stream>>>(y2, bn2part, bn2_g, bn2_b, out_W, out_b, dout);
}